// Round 1
// baseline (200.213 us; speedup 1.0000x reference)
//
#include <hip/hip_runtime.h>

#define NB 128
#define HW 64
#define STR 72           // padded LDS row stride (floats), mult of 4 for b128 alignment
#define ROWS 66
#define BUF (ROWS*STR)   // 4752 floats = 19008 B per buffer
#define LH 150
#define LQ 10

// Collapse h-conv (150ch) + 1x1 r-conv into one effective 2-in/1-out 3x3 conv.
// weff[0..17] = sum_l r_w[l]*h_w[l][c][ky][kx]  (c*9 + ky*3 + kx), weff[18] = sum_l r_w[l]*h_b[l]
__global__ void vin_prep(const float* __restrict__ h_w,
                         const float* __restrict__ h_b,
                         const float* __restrict__ r_w,
                         float* __restrict__ weff) {
    int t = threadIdx.x;
    if (t < 18) {
        float s = 0.f;
        for (int l = 0; l < LH; ++l) s += r_w[l] * h_w[l*18 + t];
        weff[t] = s;
    } else if (t == 18) {
        float s = 0.f;
        for (int l = 0; l < LH; ++l) s += r_w[l] * h_b[l];
        weff[18] = s;
    }
}

// Load 6 consecutive padded cols [3..8] relative to rowp (rowp is 16B aligned).
__device__ __forceinline__ void load_row6(const float* rowp, float* dst) {
    float2 L = *(const float2*)(rowp + 2);   // cols 2,3  (8B aligned)
    float4 M = *(const float4*)(rowp + 4);   // cols 4..7 (16B aligned)
    float  R = rowp[8];
    dst[0] = L.y; dst[1] = M.x; dst[2] = M.y; dst[3] = M.z; dst[4] = M.w; dst[5] = R;
}

// One block per image. 512 threads, each owns 2 rows x 4 cols = 8 px.
// LDS buffers have a 1-px zero halo (SAME padding) + left pad of 4 for alignment.
// Interior pixel (y,x) lives at [(1+y)*STR + 4+x]. Borders stay zero forever.
__global__ __launch_bounds__(512, 2)
void vin_main(const float* __restrict__ X,
              const float* __restrict__ q_w,
              const float* __restrict__ wgt,
              const int* __restrict__ kptr,
              const float* __restrict__ weff,
              float* __restrict__ out) {
    __shared__ float sA[BUF];   // X ch0, later v buffer 0
    __shared__ float sB[BUF];   // X ch1, later v buffer 1
    __shared__ float sC[BUF];   // r
    const int b = blockIdx.x;
    const int tid = threadIdx.x;

    for (int i = tid; i < BUF; i += 512) { sA[i] = 0.f; sB[i] = 0.f; sC[i] = 0.f; }
    __syncthreads();

    const int rp = tid >> 4, cg = tid & 15;
    const int y0 = rp * 2, x0 = cg * 4;

    // ---- stage X into LDS (coalesced float4) ----
    const float* Xb = X + (size_t)b * 2 * HW * HW;
    #pragma unroll
    for (int c = 0; c < 2; ++c) {
        float* xs = c ? sB : sA;
        #pragma unroll
        for (int ry = 0; ry < 2; ++ry) {
            float4 v = *(const float4*)(Xb + ((size_t)c*HW + y0+ry)*HW + x0);
            *(float4*)(xs + (1+y0+ry)*STR + 4 + x0) = v;
        }
    }
    __syncthreads();

    // ---- r = conv3x3(X, weff) + beff  (effective fused h->r conv) ----
    float wE[19];
    #pragma unroll
    for (int i = 0; i < 19; ++i) wE[i] = weff[i];

    float win0[4][6], win1[4][6];
    #pragma unroll
    for (int r = 0; r < 4; ++r) {
        load_row6(sA + (y0+r)*STR + x0, win0[r]);
        load_row6(sB + (y0+r)*STR + x0, win1[r]);
    }
    float rr[2][4];
    #pragma unroll
    for (int ry = 0; ry < 2; ++ry)
      #pragma unroll
      for (int rx = 0; rx < 4; ++rx) {
        float acc = wE[18];
        #pragma unroll
        for (int dy = 0; dy < 3; ++dy)
          #pragma unroll
          for (int dx = 0; dx < 3; ++dx) {
            acc += win0[ry+dy][rx+dx] * wE[dy*3+dx];
            acc += win1[ry+dy][rx+dx] * wE[9 + dy*3+dx];
          }
        rr[ry][rx] = acc;
      }
    #pragma unroll
    for (int ry = 0; ry < 2; ++ry)
      #pragma unroll
      for (int rx = 0; rx < 4; ++rx)
        sC[(1+y0+ry)*STR + 4+x0+rx] = rr[ry][rx];
    __syncthreads();

    // ---- qr[a] = conv3x3(r, q_w[a]) (loop-invariant), v0 = max_a qr[a] ----
    float winr[4][6];
    #pragma unroll
    for (int r = 0; r < 4; ++r) load_row6(sC + (y0+r)*STR + x0, winr[r]);

    float qr[LQ][2][4];
    float vcur[2][4];
    #pragma unroll
    for (int a = 0; a < LQ; ++a) {
        float wq[9];
        #pragma unroll
        for (int i = 0; i < 9; ++i) wq[i] = q_w[a*9+i];
        #pragma unroll
        for (int ry = 0; ry < 2; ++ry)
          #pragma unroll
          for (int rx = 0; rx < 4; ++rx) {
            float acc = 0.f;
            #pragma unroll
            for (int dy = 0; dy < 3; ++dy)
              #pragma unroll
              for (int dx = 0; dx < 3; ++dx)
                acc += winr[ry+dy][rx+dx] * wq[dy*3+dx];
            qr[a][ry][rx] = acc;
            vcur[ry][rx] = (a == 0) ? acc : fmaxf(vcur[ry][rx], acc);
          }
    }
    #pragma unroll
    for (int ry = 0; ry < 2; ++ry)
      #pragma unroll
      for (int rx = 0; rx < 4; ++rx)
        sA[(1+y0+ry)*STR + 4+x0+rx] = vcur[ry][rx];   // X ch0 dead; reuse as v buf 0
    __syncthreads();

    // ---- value-iteration loop: v <- max_a (qr[a] + conv3x3(v, w[a])) ----
    float wv[LQ][9];
    #pragma unroll
    for (int a = 0; a < LQ; ++a)
      #pragma unroll
      for (int i = 0; i < 9; ++i) wv[a][i] = wgt[a*9+i];

    const int km1 = kptr[0] - 1;
    float* cur = sA;
    float* nxt = sB;
    for (int it = 0; it < km1; ++it) {
        float w2[4][6];
        #pragma unroll
        for (int r = 0; r < 4; ++r) load_row6(cur + (y0+r)*STR + x0, w2[r]);
        float vn[2][4];
        #pragma unroll
        for (int a = 0; a < LQ; ++a) {
          #pragma unroll
          for (int ry = 0; ry < 2; ++ry)
            #pragma unroll
            for (int rx = 0; rx < 4; ++rx) {
              float acc = qr[a][ry][rx];
              #pragma unroll
              for (int dy = 0; dy < 3; ++dy)
                #pragma unroll
                for (int dx = 0; dx < 3; ++dx)
                  acc += w2[ry+dy][rx+dx] * wv[a][dy*3+dx];
              vn[ry][rx] = (a == 0) ? acc : fmaxf(vn[ry][rx], acc);
            }
        }
        #pragma unroll
        for (int ry = 0; ry < 2; ++ry) {
            float4 o; o.x = vn[ry][0]; o.y = vn[ry][1]; o.z = vn[ry][2]; o.w = vn[ry][3];
            *(float4*)(nxt + (1+y0+ry)*STR + 4+x0) = o;
        }
        float* t = cur; cur = nxt; nxt = t;
        __syncthreads();
    }

    // ---- write v out (coalesced float4) ----
    float* outb = out + (size_t)b * HW * HW;
    #pragma unroll
    for (int ry = 0; ry < 2; ++ry) {
        float4 o = *(const float4*)(cur + (1+y0+ry)*STR + 4 + x0);
        *(float4*)(outb + (size_t)(y0+ry)*HW + x0) = o;
    }
}

extern "C" void kernel_launch(void* const* d_in, const int* in_sizes, int n_in,
                              void* d_out, int out_size, void* d_ws, size_t ws_size,
                              hipStream_t stream) {
    const float* X   = (const float*)d_in[0];
    const float* h_w = (const float*)d_in[1];
    const float* h_b = (const float*)d_in[2];
    const float* r_w = (const float*)d_in[3];
    const float* q_w = (const float*)d_in[4];
    const float* w   = (const float*)d_in[5];
    const int*   k   = (const int*)d_in[6];
    float* out  = (float*)d_out;
    float* weff = (float*)d_ws;   // 19 floats

    vin_prep<<<1, 64, 0, stream>>>(h_w, h_b, r_w, weff);
    vin_main<<<NB, 512, 0, stream>>>(X, q_w, w, k, weff, out);
}